// Round 2
// baseline (518.023 us; speedup 1.0000x reference)
//
#include <hip/hip_runtime.h>
#include <hip/hip_bf16.h>
#include <math.h>

// Problem constants
#define B_    256
#define L_    200
#define H_    256
#define MAXT  256
#define SIXH  1536
#define FOURH 1024
#define NPOS  (B_ * L_)   // 51200

typedef __attribute__((ext_vector_type(8))) short short8;
typedef __attribute__((ext_vector_type(4))) float f32x4;

// LDS tile stride: 64 data cols + 16 pad = 80 elems = 160 B (16B-aligned rows)
#define LDS_STRIDE 80

// ---------------------------------------------------------------------------
// Transpose + f32->bf16 convert: in [R][C] f32 -> out [C][R] bf16
// ---------------------------------------------------------------------------
__global__ void transpose_to_bf16(const float* __restrict__ in,
                                  __hip_bfloat16* __restrict__ out,
                                  int R, int C) {
  __shared__ float tile[32][33];
  int tc = blockIdx.x, tr = blockIdx.y;
  int tx = threadIdx.x & 31, ty = threadIdx.x >> 5;  // 32 x 8
#pragma unroll
  for (int i = 0; i < 4; i++) {
    int r = tr * 32 + ty + i * 8;
    int c = tc * 32 + tx;
    tile[ty + i * 8][tx] = in[(size_t)r * C + c];
  }
  __syncthreads();
#pragma unroll
  for (int i = 0; i < 4; i++) {
    int orow = tc * 32 + ty + i * 8;  // out row = original col
    int ocol = tr * 32 + tx;          // out col = original row
    out[(size_t)orow * R + ocol] = __float2bfloat16(tile[tx][ty + i * 8]);
  }
}

// ---------------------------------------------------------------------------
// Fused embedding gather + concat + LayerNorm -> x bf16 [NPOS][1536]
// one block per (b,l); 256 threads; 6 channels per thread (one per table)
// ---------------------------------------------------------------------------
__global__ void embed_ln_kernel(const int* __restrict__ tok0,
                                const int* __restrict__ tok1,
                                const int* __restrict__ tok2,
                                const int* __restrict__ tok3,
                                const int* __restrict__ tgap,
                                const int* __restrict__ gid,
                                const float* __restrict__ token_emb,
                                const float* __restrict__ tg_emb,
                                const float* __restrict__ g_emb,
                                const float* __restrict__ gamma,
                                const float* __restrict__ beta,
                                __hip_bfloat16* __restrict__ xout) {
  int l = blockIdx.x, b = blockIdx.y;
  int pos = b * L_ + l;
  int t = threadIdx.x;

  int i0 = tok0[pos], i1 = tok1[pos], i2 = tok2[pos], i3 = tok3[pos];
  int it = tgap[pos];
  it = min(max(it, 0), 64);
  int ig = gid[pos];

  float v[6];
  v[0] = token_emb[(size_t)i0 * H_ + t];
  v[1] = token_emb[(size_t)i1 * H_ + t];
  v[2] = token_emb[(size_t)i2 * H_ + t];
  v[3] = token_emb[(size_t)i3 * H_ + t];
  v[4] = tg_emb[(size_t)it * H_ + t];
  v[5] = g_emb[(size_t)ig * H_ + t];

  float s = 0.f, q = 0.f;
#pragma unroll
  for (int j = 0; j < 6; j++) { s += v[j]; q += v[j] * v[j]; }
  // wave (64) reduce then cross-wave via LDS
#pragma unroll
  for (int o = 32; o; o >>= 1) { s += __shfl_down(s, o); q += __shfl_down(q, o); }
  __shared__ float ps[4], pq[4];
  int wid = t >> 6, lane = t & 63;
  if (lane == 0) { ps[wid] = s; pq[wid] = q; }
  __syncthreads();
  float ts = ps[0] + ps[1] + ps[2] + ps[3];
  float tq = pq[0] + pq[1] + pq[2] + pq[3];
  float mu = ts * (1.0f / 1536.0f);
  float var = tq * (1.0f / 1536.0f) - mu * mu;
  float rstd = rsqrtf(var + 1e-5f);
#pragma unroll
  for (int j = 0; j < 6; j++) {
    int c = j * H_ + t;
    float y = (v[j] - mu) * rstd * gamma[c] + beta[c];
    xout[(size_t)pos * SIXH + c] = __float2bfloat16(y);
  }
}

// ---------------------------------------------------------------------------
// MFMA GEMM: C[M,N] = A[M,K] * Bt[N,K]^T (+bias, epilogue)
// 128x128 tile, BK=64, 256 threads = 4 waves (2x2), each wave 64x64 out.
// EPI 0: silu -> bf16 out ; EPI 1: bias only -> f32 out
// ---------------------------------------------------------------------------
template <int EPI>
__global__ void gemm_kernel(const __hip_bfloat16* __restrict__ A,
                            const __hip_bfloat16* __restrict__ Bt,
                            const float* __restrict__ bias,
                            void* __restrict__ outp,
                            int N, int K) {
  __shared__ __hip_bfloat16 As[128][LDS_STRIDE];  // 160B rows: 16B-aligned
  __shared__ __hip_bfloat16 Bs[128][LDS_STRIDE];
  int m0 = blockIdx.y * 128;
  int n0 = blockIdx.x * 128;
  int tid = threadIdx.x;
  int lane = tid & 63, wid = tid >> 6;
  int wm = (wid >> 1) * 64, wn = (wid & 1) * 64;

  f32x4 acc[4][4] = {};

  for (int k0 = 0; k0 < K; k0 += 64) {
    // stage A and Bt tiles: 128 rows x 64 cols bf16 each; 16B chunks
#pragma unroll
    for (int c = tid; c < 1024; c += 256) {
      int row = c >> 3, col = (c & 7) * 8;
      *(short8*)&As[row][col] =
          *(const short8*)&A[(size_t)(m0 + row) * K + k0 + col];
      *(short8*)&Bs[row][col] =
          *(const short8*)&Bt[(size_t)(n0 + row) * K + k0 + col];
    }
    __syncthreads();
#pragma unroll
    for (int kk = 0; kk < 64; kk += 32) {
      short8 a[4], bb[4];
#pragma unroll
      for (int m = 0; m < 4; m++)
        a[m] = *(const short8*)&As[wm + m * 16 + (lane & 15)][kk + 8 * (lane >> 4)];
#pragma unroll
      for (int n = 0; n < 4; n++)
        bb[n] = *(const short8*)&Bs[wn + n * 16 + (lane & 15)][kk + 8 * (lane >> 4)];
#pragma unroll
      for (int m = 0; m < 4; m++)
#pragma unroll
        for (int n = 0; n < 4; n++)
          acc[m][n] = __builtin_amdgcn_mfma_f32_16x16x32_bf16(a[m], bb[n],
                                                              acc[m][n], 0, 0, 0);
    }
    __syncthreads();
  }

  // epilogue: D mapping col = lane&15, row = 4*(lane>>4)+reg
  int r0 = (lane >> 4) * 4;
  int cc = lane & 15;
#pragma unroll
  for (int m = 0; m < 4; m++)
#pragma unroll
    for (int n = 0; n < 4; n++) {
      int col = n0 + wn + n * 16 + cc;
      float bv = bias[col];
#pragma unroll
      for (int r = 0; r < 4; r++) {
        int row = m0 + wm + m * 16 + r0 + r;
        float v = acc[m][n][r] + bv;
        if (EPI == 0) {
          v = v / (1.0f + expf(-v));  // silu
          ((__hip_bfloat16*)outp)[(size_t)row * N + col] = __float2bfloat16(v);
        } else {
          ((float*)outp)[(size_t)row * N + col] = v;
        }
      }
    }
}

// ---------------------------------------------------------------------------
// Merge with separators; right-aligned scatter + pos_emb + mask; writes
// merged [B][MAXT][H] f32 then mm [B][MAXT] f32 at offset B*MAXT*H.
// one block per batch row.
// ---------------------------------------------------------------------------
__global__ void merge_kernel(const float* __restrict__ event,
                             const int* __restrict__ gids,
                             const int* __restrict__ lengths,
                             const float* __restrict__ sep_token,
                             const float* __restrict__ pos_emb,
                             float* __restrict__ out) {
  int b = blockIdx.x, t = threadIdx.x;
  __shared__ int src[MAXT];  // -1 empty, -2 sep, else token index l
  __shared__ int g[L_];
  __shared__ int sh_total;
  int len = lengths[b];
  src[t] = -1;
  for (int l = t; l < len; l += 256) g[l] = gids[b * L_ + l];
  __syncthreads();
  if (t == 0) {
    int nsep = 0;
    for (int l = 0; l + 1 < len; l++)
      if (g[l] != g[l + 1]) nsep++;
    int total = len + nsep;
    sh_total = total;
    int off = MAXT - total;
    int sb = 0;
    for (int l = 0; l < len; l++) {
      int ti = off + l + sb;
      if (ti >= 0) src[ti] = l;
      if (l + 1 < len && g[l] != g[l + 1]) {
        if (ti + 1 >= 0) src[ti + 1] = -2;
        sb++;
      }
    }
  }
  __syncthreads();
  int total = sh_total;
  int mlen = min(total, MAXT);

  float* orow = out + (size_t)b * MAXT * H_;
  for (int p = 0; p < MAXT; p++) {
    int s = src[p];
    float v;
    if (s == -1) {
      v = 0.0f;
    } else if (s == -2) {
      v = sep_token[t] + pos_emb[p * H_ + t];
    } else {
      v = event[((size_t)b * L_ + s) * H_ + t] + pos_emb[p * H_ + t];
    }
    orow[(size_t)p * H_ + t] = v;
  }
  float* mm = out + (size_t)B_ * MAXT * H_;
  mm[b * MAXT + t] = (t >= MAXT - mlen) ? 1.0f : 0.0f;
}

// ---------------------------------------------------------------------------
// launch
// ---------------------------------------------------------------------------
extern "C" void kernel_launch(void* const* d_in, const int* in_sizes, int n_in,
                              void* d_out, int out_size, void* d_ws,
                              size_t ws_size, hipStream_t stream) {
  const int* tok0 = (const int*)d_in[0];
  const int* tok1 = (const int*)d_in[1];
  const int* tok2 = (const int*)d_in[2];
  const int* tok3 = (const int*)d_in[3];
  const int* tgap = (const int*)d_in[4];
  const int* gid  = (const int*)d_in[5];
  const int* lengths = (const int*)d_in[6];
  const float* token_emb = (const float*)d_in[7];
  const float* gamma = (const float*)d_in[8];
  const float* beta  = (const float*)d_in[9];
  const float* w1 = (const float*)d_in[10];
  const float* b1 = (const float*)d_in[11];
  const float* w2 = (const float*)d_in[12];
  const float* b2 = (const float*)d_in[13];
  const float* tg_emb = (const float*)d_in[14];
  const float* g_emb  = (const float*)d_in[15];
  const float* pos_emb = (const float*)d_in[16];
  const float* sep_tok = (const float*)d_in[17];

  // workspace layout (bytes), with aliasing (x dead after GEMM1 -> event
  // reuses its region):
  //   x     bf16 [51200][1536]  @ 0          (157,286,400)
  //   event f32  [51200][256]   @ 0          ( 52,428,800)  [aliases x]
  //   h     bf16 [51200][1024]  @ 157286400  (104,857,600)
  //   w1t   bf16 [1024][1536]   @ 262144000  (  3,145,728)
  //   w2t   bf16 [256][1024]    @ 265289728  (    524,288)
  //   total 265,814,016 bytes
  const size_t NEEDED = 265814016;
  if (ws_size < NEEDED) return;  // diagnostic clean-fail instead of OOB fault

  char* ws = (char*)d_ws;
  __hip_bfloat16* x = (__hip_bfloat16*)ws;
  float* event = (float*)ws;  // aliases x (x dead after GEMM1)
  __hip_bfloat16* h = (__hip_bfloat16*)(ws + 157286400);
  __hip_bfloat16* w1t = (__hip_bfloat16*)(ws + 262144000);
  __hip_bfloat16* w2t = (__hip_bfloat16*)(ws + 265289728);

  // weights -> bf16 transposed ([N][K] for MFMA B-fragments)
  transpose_to_bf16<<<dim3(1024 / 32, 1536 / 32), 256, 0, stream>>>(w1, w1t,
                                                                    1536, 1024);
  transpose_to_bf16<<<dim3(256 / 32, 1024 / 32), 256, 0, stream>>>(w2, w2t,
                                                                   1024, 256);

  embed_ln_kernel<<<dim3(L_, B_), 256, 0, stream>>>(
      tok0, tok1, tok2, tok3, tgap, gid, token_emb, tg_emb, g_emb, gamma, beta,
      x);

  gemm_kernel<0><<<dim3(FOURH / 128, NPOS / 128), 256, 0, stream>>>(
      x, w1t, b1, (void*)h, FOURH, SIXH);

  gemm_kernel<1><<<dim3(H_ / 128, NPOS / 128), 256, 0, stream>>>(
      h, w2t, b2, (void*)event, H_, FOURH);

  merge_kernel<<<B_, 256, 0, stream>>>(event, gid, lengths, sep_tok, pos_emb,
                                       (float*)d_out);
}

// Round 3
// 307.758 us; speedup vs baseline: 1.6832x; 1.6832x over previous
//
#include <hip/hip_runtime.h>
#include <hip/hip_bf16.h>
#include <math.h>

// Problem constants
#define B_    256
#define L_    200
#define H_    256
#define MAXT  256
#define SIXH  1536
#define FOURH 1024
#define NPOS  (B_ * L_)   // 51200

typedef __attribute__((ext_vector_type(8))) short short8;
typedef __attribute__((ext_vector_type(4))) float f32x4;

typedef __attribute__((address_space(3))) void lds_void;
typedef const __attribute__((address_space(1))) void gbl_void;

// ---------------------------------------------------------------------------
// Exclusive prefix-sum of lengths -> offsets[0..B_], offsets[B_] = total valid
// ---------------------------------------------------------------------------
__global__ void scan_offsets(const int* __restrict__ lengths,
                             int* __restrict__ offsets) {
  if (threadIdx.x == 0) {
    int acc = 0;
    for (int b = 0; b < B_; b++) { offsets[b] = acc; acc += lengths[b]; }
    offsets[B_] = acc;
  }
}

// ---------------------------------------------------------------------------
// Zero the pad rows of x: rows [total, roundup128(total))
// ---------------------------------------------------------------------------
__global__ void zero_pad_x(__hip_bfloat16* __restrict__ x,
                           const int* __restrict__ offsets) {
  int total = offsets[B_];
  int padded = (total + 127) & ~127;
  int row = total + blockIdx.x;
  if (row >= padded) return;
  int t = threadIdx.x;
#pragma unroll
  for (int j = 0; j < 6; j++)
    x[(size_t)row * SIXH + j * 256 + t] = __float2bfloat16(0.0f);
}

// ---------------------------------------------------------------------------
// Transpose + f32->bf16 convert: in [R][C] f32 -> out [C][R] bf16
// ---------------------------------------------------------------------------
__global__ void transpose_to_bf16(const float* __restrict__ in,
                                  __hip_bfloat16* __restrict__ out,
                                  int R, int C) {
  __shared__ float tile[32][33];
  int tc = blockIdx.x, tr = blockIdx.y;
  int tx = threadIdx.x & 31, ty = threadIdx.x >> 5;  // 32 x 8
#pragma unroll
  for (int i = 0; i < 4; i++) {
    int r = tr * 32 + ty + i * 8;
    int c = tc * 32 + tx;
    tile[ty + i * 8][tx] = in[(size_t)r * C + c];
  }
  __syncthreads();
#pragma unroll
  for (int i = 0; i < 4; i++) {
    int orow = tc * 32 + ty + i * 8;  // out row = original col
    int ocol = tr * 32 + tx;          // out col = original row
    out[(size_t)orow * R + ocol] = __float2bfloat16(tile[tx][ty + i * 8]);
  }
}

// ---------------------------------------------------------------------------
// Fused embedding gather + concat + LayerNorm -> x bf16 [row][1536], where
// row = offsets[b] + l (valid-position compaction; invalid blocks exit).
// ---------------------------------------------------------------------------
__global__ void embed_ln_kernel(const int* __restrict__ tok0,
                                const int* __restrict__ tok1,
                                const int* __restrict__ tok2,
                                const int* __restrict__ tok3,
                                const int* __restrict__ tgap,
                                const int* __restrict__ gid,
                                const int* __restrict__ lengths,
                                const int* __restrict__ offsets,
                                const float* __restrict__ token_emb,
                                const float* __restrict__ tg_emb,
                                const float* __restrict__ g_emb,
                                const float* __restrict__ gamma,
                                const float* __restrict__ beta,
                                __hip_bfloat16* __restrict__ xout) {
  int l = blockIdx.x, b = blockIdx.y;
  if (l >= lengths[b]) return;  // compaction: skip invalid positions
  int pos = b * L_ + l;
  int row = offsets[b] + l;
  int t = threadIdx.x;

  int i0 = tok0[pos], i1 = tok1[pos], i2 = tok2[pos], i3 = tok3[pos];
  int it = tgap[pos];
  it = min(max(it, 0), 64);
  int ig = gid[pos];

  float v[6];
  v[0] = token_emb[(size_t)i0 * H_ + t];
  v[1] = token_emb[(size_t)i1 * H_ + t];
  v[2] = token_emb[(size_t)i2 * H_ + t];
  v[3] = token_emb[(size_t)i3 * H_ + t];
  v[4] = tg_emb[(size_t)it * H_ + t];
  v[5] = g_emb[(size_t)ig * H_ + t];

  float s = 0.f, q = 0.f;
#pragma unroll
  for (int j = 0; j < 6; j++) { s += v[j]; q += v[j] * v[j]; }
#pragma unroll
  for (int o = 32; o; o >>= 1) { s += __shfl_down(s, o); q += __shfl_down(q, o); }
  __shared__ float ps[4], pq[4];
  int wid = t >> 6, lane = t & 63;
  if (lane == 0) { ps[wid] = s; pq[wid] = q; }
  __syncthreads();
  float ts = ps[0] + ps[1] + ps[2] + ps[3];
  float tq = pq[0] + pq[1] + pq[2] + pq[3];
  float mu = ts * (1.0f / 1536.0f);
  float var = tq * (1.0f / 1536.0f) - mu * mu;
  float rstd = rsqrtf(var + 1e-5f);
#pragma unroll
  for (int j = 0; j < 6; j++) {
    int c = j * H_ + t;
    float y = (v[j] - mu) * rstd * gamma[c] + beta[c];
    xout[(size_t)row * SIXH + c] = __float2bfloat16(y);
  }
}

// ---------------------------------------------------------------------------
// MFMA GEMM: C[M,N] = A[M,K] * Bt[N,K]^T (+bias, epilogue)
// 128x128 tile, BK=64, 256 threads = 4 waves (2x2), each wave 64x64 out.
// Staging via global_load_lds width=16 into LINEAR LDS [128][64]
// (wave-uniform dest + lane*16 — no padding allowed).
// EPI 0: silu -> bf16 out ; EPI 1: bias only -> f32 out
// M is dynamic: tile-rows beyond roundup128(total) exit early (static grid).
// ---------------------------------------------------------------------------
template <int EPI>
__global__ void gemm_kernel(const __hip_bfloat16* __restrict__ A,
                            const __hip_bfloat16* __restrict__ Bt,
                            const float* __restrict__ bias,
                            void* __restrict__ outp,
                            const int* __restrict__ total_ptr,
                            int N, int K) {
  int m0 = blockIdx.y * 128;
  int total = total_ptr[0];
  int padded = (total + 127) & ~127;
  if (m0 >= padded) return;

  __shared__ __hip_bfloat16 As[128 * 64];  // linear: row*64 + col
  __shared__ __hip_bfloat16 Bs[128 * 64];
  int n0 = blockIdx.x * 128;
  int tid = threadIdx.x;
  int lane = tid & 63, wid = tid >> 6;
  int wm = (wid >> 1) * 64, wn = (wid & 1) * 64;

  // staging geometry: 16 chunks of 1KB per operand; wave w does chunks
  // w*4..w*4+3. lane l in chunk c covers row = c*8 + l/8, col = (l%8)*8.
  int srow = (lane >> 3);       // 0..7 within chunk
  int scol = (lane & 7) * 8;    // 0,8,..,56

  f32x4 acc[4][4] = {};

  for (int k0 = 0; k0 < K; k0 += 64) {
#pragma unroll
    for (int i = 0; i < 4; i++) {
      int c = wid * 4 + i;
      int row = c * 8 + srow;
      __builtin_amdgcn_global_load_lds(
          (gbl_void*)&A[(size_t)(m0 + row) * K + k0 + scol],
          (lds_void*)(As + c * 512), 16, 0, 0);
      __builtin_amdgcn_global_load_lds(
          (gbl_void*)&Bt[(size_t)(n0 + row) * K + k0 + scol],
          (lds_void*)(Bs + c * 512), 16, 0, 0);
    }
    __syncthreads();
#pragma unroll
    for (int kk = 0; kk < 64; kk += 32) {
      short8 a[4], bb[4];
#pragma unroll
      for (int m = 0; m < 4; m++)
        a[m] = *(const short8*)&As[(wm + m * 16 + (lane & 15)) * 64 + kk +
                                   8 * (lane >> 4)];
#pragma unroll
      for (int n = 0; n < 4; n++)
        bb[n] = *(const short8*)&Bs[(wn + n * 16 + (lane & 15)) * 64 + kk +
                                    8 * (lane >> 4)];
#pragma unroll
      for (int m = 0; m < 4; m++)
#pragma unroll
        for (int n = 0; n < 4; n++)
          acc[m][n] = __builtin_amdgcn_mfma_f32_16x16x32_bf16(a[m], bb[n],
                                                              acc[m][n], 0, 0, 0);
    }
    __syncthreads();
  }

  // epilogue: D mapping col = lane&15, row = 4*(lane>>4)+reg
  int r0 = (lane >> 4) * 4;
  int cc = lane & 15;
#pragma unroll
  for (int m = 0; m < 4; m++)
#pragma unroll
    for (int n = 0; n < 4; n++) {
      int col = n0 + wn + n * 16 + cc;
      float bv = bias[col];
#pragma unroll
      for (int r = 0; r < 4; r++) {
        int row = m0 + wm + m * 16 + r0 + r;
        float v = acc[m][n][r] + bv;
        if (EPI == 0) {
          v = v / (1.0f + expf(-v));  // silu
          ((__hip_bfloat16*)outp)[(size_t)row * N + col] = __float2bfloat16(v);
        } else {
          ((float*)outp)[(size_t)row * N + col] = v;
        }
      }
    }
}

// ---------------------------------------------------------------------------
// Merge with separators; right-aligned scatter + pos_emb + mask; writes
// merged [B][MAXT][H] f32 then mm [B][MAXT] f32 at offset B*MAXT*H.
// event rows are compacted: row for (b,s) = offsets[b] + s.
// ---------------------------------------------------------------------------
__global__ void merge_kernel(const float* __restrict__ event,
                             const int* __restrict__ gids,
                             const int* __restrict__ lengths,
                             const int* __restrict__ offsets,
                             const float* __restrict__ sep_token,
                             const float* __restrict__ pos_emb,
                             float* __restrict__ out) {
  int b = blockIdx.x, t = threadIdx.x;
  __shared__ int src[MAXT];  // -1 empty, -2 sep, else token index l
  __shared__ int g[L_];
  __shared__ int sh_total;
  int len = lengths[b];
  int base = offsets[b];
  src[t] = -1;
  for (int l = t; l < len; l += 256) g[l] = gids[b * L_ + l];
  __syncthreads();
  if (t == 0) {
    int nsep = 0;
    for (int l = 0; l + 1 < len; l++)
      if (g[l] != g[l + 1]) nsep++;
    int total = len + nsep;
    sh_total = total;
    int off = MAXT - total;
    int sb = 0;
    for (int l = 0; l < len; l++) {
      int ti = off + l + sb;
      if (ti >= 0) src[ti] = l;
      if (l + 1 < len && g[l] != g[l + 1]) {
        if (ti + 1 >= 0) src[ti + 1] = -2;
        sb++;
      }
    }
  }
  __syncthreads();
  int total = sh_total;
  int mlen = min(total, MAXT);

  float* orow = out + (size_t)b * MAXT * H_;
  for (int p = 0; p < MAXT; p++) {
    int s = src[p];
    float v;
    if (s == -1) {
      v = 0.0f;
    } else if (s == -2) {
      v = sep_token[t] + pos_emb[p * H_ + t];
    } else {
      v = event[((size_t)(base + s)) * H_ + t] + pos_emb[p * H_ + t];
    }
    orow[(size_t)p * H_ + t] = v;
  }
  float* mm = out + (size_t)B_ * MAXT * H_;
  mm[b * MAXT + t] = (t >= MAXT - mlen) ? 1.0f : 0.0f;
}

// ---------------------------------------------------------------------------
// launch
// ---------------------------------------------------------------------------
extern "C" void kernel_launch(void* const* d_in, const int* in_sizes, int n_in,
                              void* d_out, int out_size, void* d_ws,
                              size_t ws_size, hipStream_t stream) {
  const int* tok0 = (const int*)d_in[0];
  const int* tok1 = (const int*)d_in[1];
  const int* tok2 = (const int*)d_in[2];
  const int* tok3 = (const int*)d_in[3];
  const int* tgap = (const int*)d_in[4];
  const int* gid  = (const int*)d_in[5];
  const int* lengths = (const int*)d_in[6];
  const float* token_emb = (const float*)d_in[7];
  const float* gamma = (const float*)d_in[8];
  const float* beta  = (const float*)d_in[9];
  const float* w1 = (const float*)d_in[10];
  const float* b1 = (const float*)d_in[11];
  const float* w2 = (const float*)d_in[12];
  const float* b2 = (const float*)d_in[13];
  const float* tg_emb = (const float*)d_in[14];
  const float* g_emb  = (const float*)d_in[15];
  const float* pos_emb = (const float*)d_in[16];
  const float* sep_tok = (const float*)d_in[17];

  // workspace layout (bytes), x dead after GEMM1 -> event aliases it:
  //   x     bf16 [<=51200][1536] @ 0          (157,286,400)
  //   event f32  [<=51200][256]  @ 0          (aliases x)
  //   h     bf16 [<=51200][1024] @ 157286400  (104,857,600)
  //   w1t   bf16 [1024][1536]    @ 262144000  (  3,145,728)
  //   w2t   bf16 [256][1024]     @ 265289728  (    524,288)
  //   offsets int[257]           @ 265814016  (      1,028)
  const size_t NEEDED = 265815044;
  if (ws_size < NEEDED) return;  // diagnostic clean-fail instead of OOB fault

  char* ws = (char*)d_ws;
  __hip_bfloat16* x = (__hip_bfloat16*)ws;
  float* event = (float*)ws;  // aliases x (x dead after GEMM1)
  __hip_bfloat16* h = (__hip_bfloat16*)(ws + 157286400);
  __hip_bfloat16* w1t = (__hip_bfloat16*)(ws + 262144000);
  __hip_bfloat16* w2t = (__hip_bfloat16*)(ws + 265289728);
  int* offsets = (int*)(ws + 265814016);

  scan_offsets<<<1, 64, 0, stream>>>(lengths, offsets);
  zero_pad_x<<<128, 256, 0, stream>>>(x, offsets);

  transpose_to_bf16<<<dim3(1024 / 32, 1536 / 32), 256, 0, stream>>>(w1, w1t,
                                                                    1536, 1024);
  transpose_to_bf16<<<dim3(256 / 32, 1024 / 32), 256, 0, stream>>>(w2, w2t,
                                                                   1024, 256);

  embed_ln_kernel<<<dim3(L_, B_), 256, 0, stream>>>(
      tok0, tok1, tok2, tok3, tgap, gid, lengths, offsets, token_emb, tg_emb,
      g_emb, gamma, beta, x);

  // M grid fixed at worst case (400 tile-rows); blocks beyond padded total
  // exit early (device-side M).
  gemm_kernel<0><<<dim3(FOURH / 128, NPOS / 128), 256, 0, stream>>>(
      x, w1t, b1, (void*)h, offsets + B_, FOURH, SIXH);

  gemm_kernel<1><<<dim3(H_ / 128, NPOS / 128), 256, 0, stream>>>(
      h, w2t, b2, (void*)event, offsets + B_, H_, FOURH);

  merge_kernel<<<B_, 256, 0, stream>>>(event, gid, lengths, offsets, sep_tok,
                                       pos_emb, (float*)d_out);
}

// Round 4
// 294.748 us; speedup vs baseline: 1.7575x; 1.0441x over previous
//
#include <hip/hip_runtime.h>
#include <hip/hip_bf16.h>
#include <math.h>

// Problem constants
#define B_    256
#define L_    200
#define H_    256
#define MAXT  256
#define SIXH  1536
#define FOURH 1024
#define NPOS  (B_ * L_)   // 51200

typedef __attribute__((ext_vector_type(8))) short short8;
typedef __attribute__((ext_vector_type(4))) float f32x4;

typedef __attribute__((address_space(3))) void lds_void;
typedef const __attribute__((address_space(1))) void gbl_void;

#define ASM_BAR() asm volatile("s_barrier" ::: "memory")
#define VMCNT4()  asm volatile("s_waitcnt vmcnt(4)" ::: "memory")
#define VMCNT0()  asm volatile("s_waitcnt vmcnt(0)" ::: "memory")

// ---------------------------------------------------------------------------
// Exclusive prefix-sum of lengths -> offsets[0..B_], offsets[B_] = total valid
// ---------------------------------------------------------------------------
__global__ void scan_offsets(const int* __restrict__ lengths,
                             int* __restrict__ offsets) {
  if (threadIdx.x == 0) {
    int acc = 0;
    for (int b = 0; b < B_; b++) { offsets[b] = acc; acc += lengths[b]; }
    offsets[B_] = acc;
  }
}

// ---------------------------------------------------------------------------
// Zero the pad rows of x: rows [total, roundup256(total))
// ---------------------------------------------------------------------------
__global__ void zero_pad_x(__hip_bfloat16* __restrict__ x,
                           const int* __restrict__ offsets) {
  int total = offsets[B_];
  int padded = (total + 255) & ~255;
  int row = total + blockIdx.x;
  if (row >= padded) return;
  int t = threadIdx.x;
#pragma unroll
  for (int j = 0; j < 6; j++)
    x[(size_t)row * SIXH + j * 256 + t] = __float2bfloat16(0.0f);
}

// ---------------------------------------------------------------------------
// Transpose + f32->bf16 convert: in [R][C] f32 -> out [C][R] bf16
// ---------------------------------------------------------------------------
__global__ void transpose_to_bf16(const float* __restrict__ in,
                                  __hip_bfloat16* __restrict__ out,
                                  int R, int C) {
  __shared__ float tile[32][33];
  int tc = blockIdx.x, tr = blockIdx.y;
  int tx = threadIdx.x & 31, ty = threadIdx.x >> 5;  // 32 x 8
#pragma unroll
  for (int i = 0; i < 4; i++) {
    int r = tr * 32 + ty + i * 8;
    int c = tc * 32 + tx;
    tile[ty + i * 8][tx] = in[(size_t)r * C + c];
  }
  __syncthreads();
#pragma unroll
  for (int i = 0; i < 4; i++) {
    int orow = tc * 32 + ty + i * 8;  // out row = original col
    int ocol = tr * 32 + tx;          // out col = original row
    out[(size_t)orow * R + ocol] = __float2bfloat16(tile[tx][ty + i * 8]);
  }
}

// ---------------------------------------------------------------------------
// Fused embedding gather + concat + LayerNorm -> x bf16 [row][1536]
// 384 threads = 6 waves; wave j handles table j; thread = float4 (4 channels).
// ---------------------------------------------------------------------------
__global__ void embed_ln_kernel(const int* __restrict__ tok0,
                                const int* __restrict__ tok1,
                                const int* __restrict__ tok2,
                                const int* __restrict__ tok3,
                                const int* __restrict__ tgap,
                                const int* __restrict__ gid,
                                const int* __restrict__ lengths,
                                const int* __restrict__ offsets,
                                const float* __restrict__ token_emb,
                                const float* __restrict__ tg_emb,
                                const float* __restrict__ g_emb,
                                const float* __restrict__ gamma,
                                const float* __restrict__ beta,
                                __hip_bfloat16* __restrict__ xout) {
  int l = blockIdx.x, b = blockIdx.y;
  if (l >= lengths[b]) return;  // compaction: skip invalid positions
  int pos = b * L_ + l;
  int row = offsets[b] + l;
  int t = threadIdx.x;
  int wv = t >> 6;          // table index 0..5
  int ln = t & 63;
  int c4 = ln * 4;          // channel within table

  // pick table + index for this wave
  const float* tab;
  int idx;
  if (wv == 0)      { tab = token_emb; idx = tok0[pos]; }
  else if (wv == 1) { tab = token_emb; idx = tok1[pos]; }
  else if (wv == 2) { tab = token_emb; idx = tok2[pos]; }
  else if (wv == 3) { tab = token_emb; idx = tok3[pos]; }
  else if (wv == 4) { tab = tg_emb;    idx = min(max(tgap[pos], 0), 64); }
  else              { tab = g_emb;     idx = gid[pos]; }

  float4 v = *(const float4*)&tab[(size_t)idx * H_ + c4];

  float s = v.x + v.y + v.z + v.w;
  float q = v.x * v.x + v.y * v.y + v.z * v.z + v.w * v.w;
#pragma unroll
  for (int o = 32; o; o >>= 1) { s += __shfl_down(s, o); q += __shfl_down(q, o); }
  __shared__ float ps[6], pq[6];
  if (ln == 0) { ps[wv] = s; pq[wv] = q; }
  __syncthreads();
  float ts = 0.f, tq = 0.f;
#pragma unroll
  for (int k = 0; k < 6; k++) { ts += ps[k]; tq += pq[k]; }
  float mu = ts * (1.0f / 1536.0f);
  float var = tq * (1.0f / 1536.0f) - mu * mu;
  float rstd = rsqrtf(var + 1e-5f);

  int cbase = wv * 256 + c4;
  float4 gm = *(const float4*)&gamma[cbase];
  float4 bt = *(const float4*)&beta[cbase];
  float y0 = (v.x - mu) * rstd * gm.x + bt.x;
  float y1 = (v.y - mu) * rstd * gm.y + bt.y;
  float y2 = (v.z - mu) * rstd * gm.z + bt.z;
  float y3 = (v.w - mu) * rstd * gm.w + bt.w;
  __hip_bfloat16 h0 = __float2bfloat16(y0), h1 = __float2bfloat16(y1);
  __hip_bfloat16 h2 = __float2bfloat16(y2), h3 = __float2bfloat16(y3);
  ushort4 pk;
  pk.x = *(unsigned short*)&h0; pk.y = *(unsigned short*)&h1;
  pk.z = *(unsigned short*)&h2; pk.w = *(unsigned short*)&h3;
  *(ushort4*)&xout[(size_t)row * SIXH + cbase] = pk;
}

// ---------------------------------------------------------------------------
// GEMM1: 256x256 tile, BK=64, 8 waves, 8-phase pipelined schedule with
// counted vmcnt(4), K-half-split LDS regions, XOR-swizzled pair-packed layout
// (contiguous 16KB half-tiles => linear global_load_lds; even bank use on
// ds_read_b128). Epilogue: bias + SiLU -> bf16.
//
// LDS map (128 KiB dynamic): buffer d in {0,1} at d*65536;
//   A khalf h at +h*16384 ; B khalf h at +32768 + h*16384.
// Region layout (256 rows x 32 cols bf16 = 16KB):
//   lds_row = row>>1 (128B lines), slot = (((row&1)<<2)|(col>>3)) ^ (lds_row&7)
//   byte = lds_row*128 + slot*16 + (col&7)*2
// ---------------------------------------------------------------------------
__global__ __launch_bounds__(512, 2)
void gemm1_8ph(const __hip_bfloat16* __restrict__ A,
               const __hip_bfloat16* __restrict__ Bt,
               const float* __restrict__ bias,
               __hip_bfloat16* __restrict__ out,
               const int* __restrict__ total_ptr) {
  constexpr int K = SIXH;     // 1536
  constexpr int NT = K / 64;  // 24 K-tiles
  constexpr int N = FOURH;    // 1024

  extern __shared__ __align__(16) char lds[];

  int total = total_ptr[0];
  int padded = (total + 255) & ~255;

  // XCD-aware remap: grid (4, 200) -> flat; same-A-panel n-tiles co-XCD;
  // m-tiles interleaved mod 8 so compaction early-exits stay balanced.
  int flat = blockIdx.y * 4 + blockIdx.x;
  int xcd = flat & 7, idx = flat >> 3;
  int mt = (idx >> 2) * 8 + xcd;  // 0..199
  int nt = idx & 3;               // 0..3
  int m0 = mt * 256;
  int n0 = nt * 256;
  if (m0 >= padded) return;

  int tid = threadIdx.x;
  int lane = tid & 63;
  int w = tid >> 6;        // wave 0..7
  int wave_m = w >> 2;     // 0..1  (rows wave_m*128 .. +128)
  int wave_n = w & 3;      // 0..3  (cols wave_n*64 .. +64)

  // fragment-read lane offset (16B-aligned, derived from layout above)
  int r15 = lane & 15, g = lane >> 4;
  int slot_r = (((r15 & 1) << 2) | g) ^ (r15 >> 1);
  int lane_off = (r15 >> 1) * 128 + slot_r * 16;

  // staging source mapping: thread t, instr i writes region bytes
  // i*8192 + t*16 .. +15  -> source (row, col) below (inverse of layout)
  int s0 = (tid & 7) ^ ((tid >> 3) & 7);
  int scol = (s0 & 3) * 8;                      // elem col within khalf
  int row0 = ((tid >> 3) << 1) + (s0 >> 2);     // instr0 row; instr1 = +128
  int ldst0 = w * 1024;                         // wave-uniform LDS dest off

#define REGA(d, h) (lds + (d) * 65536 + (h) * 16384)
#define REGB(d, h) (lds + (d) * 65536 + 32768 + (h) * 16384)

#define STAGE(P, t0, kt, h, rb)                                                \
  do {                                                                         \
    __builtin_amdgcn_global_load_lds(                                          \
        (gbl_void*)((P) + (size_t)((t0) + row0) * K + (kt) * 64 + (h) * 32 +   \
                    scol),                                                     \
        (lds_void*)((rb) + ldst0), 16, 0, 0);                                  \
    __builtin_amdgcn_global_load_lds(                                          \
        (gbl_void*)((P) + (size_t)((t0) + row0 + 128) * K + (kt) * 64 +        \
                    (h) * 32 + scol),                                          \
        (lds_void*)((rb) + 8192 + ldst0), 16, 0, 0);                           \
  } while (0)

  f32x4 acc[8][4] = {};

  // prologue: kt0 fully + kt1 khalf0 ; then all of kt0 resident (4 in flight)
  STAGE(A, m0, 0, 0, REGA(0, 0));
  STAGE(Bt, n0, 0, 0, REGB(0, 0));
  STAGE(A, m0, 0, 1, REGA(0, 1));
  STAGE(Bt, n0, 0, 1, REGB(0, 1));
  STAGE(A, m0, 1, 0, REGA(1, 0));
  STAGE(Bt, n0, 1, 0, REGB(1, 0));
  VMCNT4();
  ASM_BAR();

  for (int kt = 0; kt < NT; ++kt) {
    int d = kt & 1;
    int kc1 = (kt + 1 < NT) ? kt + 1 : NT - 1;  // clamped (redundant loads ok)
    int kc2 = (kt + 2 < NT) ? kt + 2 : NT - 1;
    char* A0 = REGA(d, 0); char* A1 = REGA(d, 1);
    char* B0 = REGB(d, 0); char* B1 = REGB(d, 1);
    char* An1 = REGA(d ^ 1, 1);
    char* Bn1 = REGB(d ^ 1, 1);

    short8 a[4], b[4];

    // ---- phase 0: kh0, mi 0-3 ; stage A(kt+1, kh1)
#pragma unroll
    for (int ni = 0; ni < 4; ni++)
      b[ni] = *(const short8*)(B0 + (wave_n * 64 + ni * 16) * 64 + lane_off);
#pragma unroll
    for (int j = 0; j < 4; j++)
      a[j] = *(const short8*)(A0 + (wave_m * 128 + j * 16) * 64 + lane_off);
    STAGE(A, m0, kc1, 1, An1);
    ASM_BAR();
    __builtin_amdgcn_s_setprio(1);
#pragma unroll
    for (int j = 0; j < 4; j++)
#pragma unroll
      for (int ni = 0; ni < 4; ni++)
        acc[j][ni] =
            __builtin_amdgcn_mfma_f32_16x16x32_bf16(a[j], b[ni], acc[j][ni], 0, 0, 0);
    __builtin_amdgcn_s_setprio(0);
    ASM_BAR();

    // ---- phase 1: kh0, mi 4-7 ; stage B(kt+1, kh1)
#pragma unroll
    for (int j = 0; j < 4; j++)
      a[j] = *(const short8*)(A0 + (wave_m * 128 + (4 + j) * 16) * 64 + lane_off);
    STAGE(Bt, n0, kc1, 1, Bn1);
    ASM_BAR();
    __builtin_amdgcn_s_setprio(1);
#pragma unroll
    for (int j = 0; j < 4; j++)
#pragma unroll
      for (int ni = 0; ni < 4; ni++)
        acc[4 + j][ni] =
            __builtin_amdgcn_mfma_f32_16x16x32_bf16(a[j], b[ni], acc[4 + j][ni], 0, 0, 0);
    __builtin_amdgcn_s_setprio(0);
    ASM_BAR();

    // ---- phase 2: kh1, mi 0-3 ; stage A(kt+2, kh0) -> overwrites A0 (dead)
#pragma unroll
    for (int ni = 0; ni < 4; ni++)
      b[ni] = *(const short8*)(B1 + (wave_n * 64 + ni * 16) * 64 + lane_off);
#pragma unroll
    for (int j = 0; j < 4; j++)
      a[j] = *(const short8*)(A1 + (wave_m * 128 + j * 16) * 64 + lane_off);
    STAGE(A, m0, kc2, 0, A0);
    ASM_BAR();
    __builtin_amdgcn_s_setprio(1);
#pragma unroll
    for (int j = 0; j < 4; j++)
#pragma unroll
      for (int ni = 0; ni < 4; ni++)
        acc[j][ni] =
            __builtin_amdgcn_mfma_f32_16x16x32_bf16(a[j], b[ni], acc[j][ni], 0, 0, 0);
    __builtin_amdgcn_s_setprio(0);
    ASM_BAR();

    // ---- phase 3: kh1, mi 4-7 ; stage B(kt+2, kh0) ; counted vmcnt(4)
#pragma unroll
    for (int j = 0; j < 4; j++)
      a[j] = *(const short8*)(A1 + (wave_m * 128 + (4 + j) * 16) * 64 + lane_off);
    STAGE(Bt, n0, kc2, 0, B0);
    ASM_BAR();
    __builtin_amdgcn_s_setprio(1);
#pragma unroll
    for (int j = 0; j < 4; j++)
#pragma unroll
      for (int ni = 0; ni < 4; ni++)
        acc[4 + j][ni] =
            __builtin_amdgcn_mfma_f32_16x16x32_bf16(a[j], b[ni], acc[4 + j][ni], 0, 0, 0);
    __builtin_amdgcn_s_setprio(0);
    VMCNT4();   // newest 4 loads (kt+2 kh0) may stay in flight
    ASM_BAR();
  }
  VMCNT0();  // drain before LDS goes out of scope

  // epilogue: D mapping col = lane&15, row = 4*(lane>>4)+reg
  int r0 = g * 4;
  int cc = r15;
#pragma unroll
  for (int mi = 0; mi < 8; mi++)
#pragma unroll
    for (int ni = 0; ni < 4; ni++) {
      int col = n0 + wave_n * 64 + ni * 16 + cc;
      float bv = bias[col];
#pragma unroll
      for (int r = 0; r < 4; r++) {
        int row = m0 + wave_m * 128 + mi * 16 + r0 + r;
        float v = acc[mi][ni][r] + bv;
        v = v / (1.0f + __expf(-v));  // silu
        out[(size_t)row * N + col] = __float2bfloat16(v);
      }
    }
#undef STAGE
#undef REGA
#undef REGB
}

// ---------------------------------------------------------------------------
// GEMM2 (unchanged, verified): 128x128 tile, linear-LDS global_load_lds.
// C = A[M,K] * Bt[N,K]^T + bias -> f32
// ---------------------------------------------------------------------------
__global__ void gemm2_kernel(const __hip_bfloat16* __restrict__ A,
                             const __hip_bfloat16* __restrict__ Bt,
                             const float* __restrict__ bias,
                             float* __restrict__ outp,
                             const int* __restrict__ total_ptr,
                             int N, int K) {
  int m0 = blockIdx.y * 128;
  int total = total_ptr[0];
  int padded = (total + 127) & ~127;
  if (m0 >= padded) return;

  __shared__ __hip_bfloat16 As[128 * 64];
  __shared__ __hip_bfloat16 Bs[128 * 64];
  int n0 = blockIdx.x * 128;
  int tid = threadIdx.x;
  int lane = tid & 63, wid = tid >> 6;
  int wm = (wid >> 1) * 64, wn = (wid & 1) * 64;

  int srow = (lane >> 3);
  int scol = (lane & 7) * 8;

  f32x4 acc[4][4] = {};

  for (int k0 = 0; k0 < K; k0 += 64) {
#pragma unroll
    for (int i = 0; i < 4; i++) {
      int c = wid * 4 + i;
      int row = c * 8 + srow;
      __builtin_amdgcn_global_load_lds(
          (gbl_void*)&A[(size_t)(m0 + row) * K + k0 + scol],
          (lds_void*)(As + c * 512), 16, 0, 0);
      __builtin_amdgcn_global_load_lds(
          (gbl_void*)&Bt[(size_t)(n0 + row) * K + k0 + scol],
          (lds_void*)(Bs + c * 512), 16, 0, 0);
    }
    __syncthreads();
#pragma unroll
    for (int kk = 0; kk < 64; kk += 32) {
      short8 a[4], bb[4];
#pragma unroll
      for (int m = 0; m < 4; m++)
        a[m] = *(const short8*)&As[(wm + m * 16 + (lane & 15)) * 64 + kk +
                                   8 * (lane >> 4)];
#pragma unroll
      for (int n = 0; n < 4; n++)
        bb[n] = *(const short8*)&Bs[(wn + n * 16 + (lane & 15)) * 64 + kk +
                                    8 * (lane >> 4)];
#pragma unroll
      for (int m = 0; m < 4; m++)
#pragma unroll
        for (int n = 0; n < 4; n++)
          acc[m][n] = __builtin_amdgcn_mfma_f32_16x16x32_bf16(a[m], bb[n],
                                                              acc[m][n], 0, 0, 0);
    }
    __syncthreads();
  }

  int r0 = (lane >> 4) * 4;
  int cc = lane & 15;
#pragma unroll
  for (int m = 0; m < 4; m++)
#pragma unroll
    for (int n = 0; n < 4; n++) {
      int col = n0 + wn + n * 16 + cc;
      float bv = bias[col];
#pragma unroll
      for (int r = 0; r < 4; r++) {
        int row = m0 + wm + m * 16 + r0 + r;
        outp[(size_t)row * N + col] = acc[m][n][r] + bv;
      }
    }
}

// ---------------------------------------------------------------------------
// Merge with separators (unchanged)
// ---------------------------------------------------------------------------
__global__ void merge_kernel(const float* __restrict__ event,
                             const int* __restrict__ gids,
                             const int* __restrict__ lengths,
                             const int* __restrict__ offsets,
                             const float* __restrict__ sep_token,
                             const float* __restrict__ pos_emb,
                             float* __restrict__ out) {
  int b = blockIdx.x, t = threadIdx.x;
  __shared__ int src[MAXT];
  __shared__ int g[L_];
  __shared__ int sh_total;
  int len = lengths[b];
  int base = offsets[b];
  src[t] = -1;
  for (int l = t; l < len; l += 256) g[l] = gids[b * L_ + l];
  __syncthreads();
  if (t == 0) {
    int nsep = 0;
    for (int l = 0; l + 1 < len; l++)
      if (g[l] != g[l + 1]) nsep++;
    int total = len + nsep;
    sh_total = total;
    int off = MAXT - total;
    int sb = 0;
    for (int l = 0; l < len; l++) {
      int ti = off + l + sb;
      if (ti >= 0) src[ti] = l;
      if (l + 1 < len && g[l] != g[l + 1]) {
        if (ti + 1 >= 0) src[ti + 1] = -2;
        sb++;
      }
    }
  }
  __syncthreads();
  int total = sh_total;
  int mlen = min(total, MAXT);

  float* orow = out + (size_t)b * MAXT * H_;
  for (int p = 0; p < MAXT; p++) {
    int s = src[p];
    float v;
    if (s == -1) {
      v = 0.0f;
    } else if (s == -2) {
      v = sep_token[t] + pos_emb[p * H_ + t];
    } else {
      v = event[((size_t)(base + s)) * H_ + t] + pos_emb[p * H_ + t];
    }
    orow[(size_t)p * H_ + t] = v;
  }
  float* mm = out + (size_t)B_ * MAXT * H_;
  mm[b * MAXT + t] = (t >= MAXT - mlen) ? 1.0f : 0.0f;
}

// ---------------------------------------------------------------------------
// launch
// ---------------------------------------------------------------------------
extern "C" void kernel_launch(void* const* d_in, const int* in_sizes, int n_in,
                              void* d_out, int out_size, void* d_ws,
                              size_t ws_size, hipStream_t stream) {
  const int* tok0 = (const int*)d_in[0];
  const int* tok1 = (const int*)d_in[1];
  const int* tok2 = (const int*)d_in[2];
  const int* tok3 = (const int*)d_in[3];
  const int* tgap = (const int*)d_in[4];
  const int* gid  = (const int*)d_in[5];
  const int* lengths = (const int*)d_in[6];
  const float* token_emb = (const float*)d_in[7];
  const float* gamma = (const float*)d_in[8];
  const float* beta  = (const float*)d_in[9];
  const float* w1 = (const float*)d_in[10];
  const float* b1 = (const float*)d_in[11];
  const float* w2 = (const float*)d_in[12];
  const float* b2 = (const float*)d_in[13];
  const float* tg_emb = (const float*)d_in[14];
  const float* g_emb  = (const float*)d_in[15];
  const float* pos_emb = (const float*)d_in[16];
  const float* sep_tok = (const float*)d_in[17];

  // workspace layout (bytes); x dead after GEMM1 -> event aliases it:
  //   x     bf16 [<=51200][1536] @ 0          (157,286,400)
  //   event f32  [<=51200][256]  @ 0          (aliases x)
  //   h     bf16 [<=51200][1024] @ 157286400  (104,857,600)
  //   w1t   bf16 [1024][1536]    @ 262144000  (  3,145,728)
  //   w2t   bf16 [256][1024]     @ 265289728  (    524,288)
  //   offsets int[257]           @ 265814016  (      1,028)
  const size_t NEEDED = 265815044;
  if (ws_size < NEEDED) return;

  char* ws = (char*)d_ws;
  __hip_bfloat16* x = (__hip_bfloat16*)ws;
  float* event = (float*)ws;
  __hip_bfloat16* h = (__hip_bfloat16*)(ws + 157286400);
  __hip_bfloat16* w1t = (__hip_bfloat16*)(ws + 262144000);
  __hip_bfloat16* w2t = (__hip_bfloat16*)(ws + 265289728);
  int* offsets = (int*)(ws + 265814016);

  scan_offsets<<<1, 64, 0, stream>>>(lengths, offsets);
  zero_pad_x<<<256, 256, 0, stream>>>(x, offsets);

  transpose_to_bf16<<<dim3(1024 / 32, 1536 / 32), 256, 0, stream>>>(w1, w1t,
                                                                    1536, 1024);
  transpose_to_bf16<<<dim3(256 / 32, 1024 / 32), 256, 0, stream>>>(w2, w2t,
                                                                   1024, 256);

  embed_ln_kernel<<<dim3(L_, B_), 384, 0, stream>>>(
      tok0, tok1, tok2, tok3, tgap, gid, lengths, offsets, token_emb, tg_emb,
      g_emb, gamma, beta, x);

  // GEMM1: 256^2 8-phase; static grid (4 n-tiles, 200 m-tiles), early exit.
  hipFuncSetAttribute((const void*)gemm1_8ph,
                      hipFuncAttributeMaxDynamicSharedMemorySize, 131072);
  gemm1_8ph<<<dim3(4, NPOS / 256), 512, 131072, stream>>>(x, w1t, b1, h,
                                                          offsets + B_);

  gemm2_kernel<<<dim3(H_ / 128, NPOS / 128), 256, 0, stream>>>(
      h, w2t, b2, event, offsets + B_, H_, FOURH);

  merge_kernel<<<B_, 256, 0, stream>>>(event, gid, lengths, offsets, sep_tok,
                                       pos_emb, (float*)d_out);
}

// Round 5
// 258.434 us; speedup vs baseline: 2.0045x; 1.1405x over previous
//
#include <hip/hip_runtime.h>
#include <hip/hip_bf16.h>
#include <math.h>

// Problem constants
#define B_    256
#define L_    200
#define H_    256
#define MAXT  256
#define SIXH  1536
#define FOURH 1024
#define NPOS  (B_ * L_)   // 51200

typedef __attribute__((ext_vector_type(8))) short short8;
typedef __attribute__((ext_vector_type(4))) float f32x4;

typedef __attribute__((address_space(3))) void lds_void;
typedef const __attribute__((address_space(1))) void gbl_void;

#define ASM_BAR() asm volatile("s_barrier" ::: "memory")
#define VMCNT4()  asm volatile("s_waitcnt vmcnt(4)" ::: "memory")
#define VMCNT0()  asm volatile("s_waitcnt vmcnt(0)" ::: "memory")

// ---------------------------------------------------------------------------
// Exclusive prefix-sum of lengths -> offsets[0..B_], offsets[B_] = total valid
// ---------------------------------------------------------------------------
__global__ void scan_offsets(const int* __restrict__ lengths,
                             int* __restrict__ offsets) {
  if (threadIdx.x == 0) {
    int acc = 0;
    for (int b = 0; b < B_; b++) { offsets[b] = acc; acc += lengths[b]; }
    offsets[B_] = acc;
  }
}

// ---------------------------------------------------------------------------
// Zero the pad rows of x: rows [total, roundup256(total))
// ---------------------------------------------------------------------------
__global__ void zero_pad_x(__hip_bfloat16* __restrict__ x,
                           const int* __restrict__ offsets) {
  int total = offsets[B_];
  int padded = (total + 255) & ~255;
  int row = total + blockIdx.x;
  if (row >= padded) return;
  int t = threadIdx.x;
#pragma unroll
  for (int j = 0; j < 6; j++)
    x[(size_t)row * SIXH + j * 256 + t] = __float2bfloat16(0.0f);
}

// ---------------------------------------------------------------------------
// Per compacted row: absolute output slot b*MAXT+p (or -1). Same scan as
// the merge logic (right-aligned, sep after group change).
// ---------------------------------------------------------------------------
__global__ void tpos_kernel(const int* __restrict__ gids,
                            const int* __restrict__ lengths,
                            const int* __restrict__ offsets,
                            int* __restrict__ tpos) {
  int b = blockIdx.x;
  if (threadIdx.x != 0) return;
  int len = lengths[b];
  int base = offsets[b];
  const int* g = gids + b * L_;
  int nsep = 0;
  for (int l = 0; l + 1 < len; l++)
    if (g[l] != g[l + 1]) nsep++;
  int total = len + nsep;
  int off = MAXT - total;
  int sb = 0;
  for (int l = 0; l < len; l++) {
    int ti = off + l + sb;
    tpos[base + l] = (ti >= 0) ? (b * MAXT + ti) : -1;
    if (l + 1 < len && g[l] != g[l + 1]) sb++;
  }
}

// ---------------------------------------------------------------------------
// Transpose + f32->bf16 convert: in [R][C] f32 -> out [C][R] bf16
// ---------------------------------------------------------------------------
__global__ void transpose_to_bf16(const float* __restrict__ in,
                                  __hip_bfloat16* __restrict__ out,
                                  int R, int C) {
  __shared__ float tile[32][33];
  int tc = blockIdx.x, tr = blockIdx.y;
  int tx = threadIdx.x & 31, ty = threadIdx.x >> 5;  // 32 x 8
#pragma unroll
  for (int i = 0; i < 4; i++) {
    int r = tr * 32 + ty + i * 8;
    int c = tc * 32 + tx;
    tile[ty + i * 8][tx] = in[(size_t)r * C + c];
  }
  __syncthreads();
#pragma unroll
  for (int i = 0; i < 4; i++) {
    int orow = tc * 32 + ty + i * 8;  // out row = original col
    int ocol = tr * 32 + tx;          // out col = original row
    out[(size_t)orow * R + ocol] = __float2bfloat16(tile[tx][ty + i * 8]);
  }
}

// ---------------------------------------------------------------------------
// Fused embedding gather + concat + LayerNorm -> x bf16 [row][1536]
// 384 threads = 6 waves; wave j handles table j; thread = float4 (4 channels).
// ---------------------------------------------------------------------------
__global__ void embed_ln_kernel(const int* __restrict__ tok0,
                                const int* __restrict__ tok1,
                                const int* __restrict__ tok2,
                                const int* __restrict__ tok3,
                                const int* __restrict__ tgap,
                                const int* __restrict__ gid,
                                const int* __restrict__ lengths,
                                const int* __restrict__ offsets,
                                const float* __restrict__ token_emb,
                                const float* __restrict__ tg_emb,
                                const float* __restrict__ g_emb,
                                const float* __restrict__ gamma,
                                const float* __restrict__ beta,
                                __hip_bfloat16* __restrict__ xout) {
  int l = blockIdx.x, b = blockIdx.y;
  if (l >= lengths[b]) return;  // compaction: skip invalid positions
  int pos = b * L_ + l;
  int row = offsets[b] + l;
  int t = threadIdx.x;
  int wv = t >> 6;          // table index 0..5
  int ln = t & 63;
  int c4 = ln * 4;          // channel within table

  const float* tab;
  int idx;
  if (wv == 0)      { tab = token_emb; idx = tok0[pos]; }
  else if (wv == 1) { tab = token_emb; idx = tok1[pos]; }
  else if (wv == 2) { tab = token_emb; idx = tok2[pos]; }
  else if (wv == 3) { tab = token_emb; idx = tok3[pos]; }
  else if (wv == 4) { tab = tg_emb;    idx = min(max(tgap[pos], 0), 64); }
  else              { tab = g_emb;     idx = gid[pos]; }

  float4 v = *(const float4*)&tab[(size_t)idx * H_ + c4];

  float s = v.x + v.y + v.z + v.w;
  float q = v.x * v.x + v.y * v.y + v.z * v.z + v.w * v.w;
#pragma unroll
  for (int o = 32; o; o >>= 1) { s += __shfl_down(s, o); q += __shfl_down(q, o); }
  __shared__ float ps[6], pq[6];
  if (ln == 0) { ps[wv] = s; pq[wv] = q; }
  __syncthreads();
  float ts = 0.f, tq = 0.f;
#pragma unroll
  for (int k = 0; k < 6; k++) { ts += ps[k]; tq += pq[k]; }
  float mu = ts * (1.0f / 1536.0f);
  float var = tq * (1.0f / 1536.0f) - mu * mu;
  float rstd = rsqrtf(var + 1e-5f);

  int cbase = wv * 256 + c4;
  float4 gm = *(const float4*)&gamma[cbase];
  float4 bt = *(const float4*)&beta[cbase];
  float y0 = (v.x - mu) * rstd * gm.x + bt.x;
  float y1 = (v.y - mu) * rstd * gm.y + bt.y;
  float y2 = (v.z - mu) * rstd * gm.z + bt.z;
  float y3 = (v.w - mu) * rstd * gm.w + bt.w;
  __hip_bfloat16 h0 = __float2bfloat16(y0), h1 = __float2bfloat16(y1);
  __hip_bfloat16 h2 = __float2bfloat16(y2), h3 = __float2bfloat16(y3);
  ushort4 pk;
  pk.x = *(unsigned short*)&h0; pk.y = *(unsigned short*)&h1;
  pk.z = *(unsigned short*)&h2; pk.w = *(unsigned short*)&h3;
  *(ushort4*)&xout[(size_t)row * SIXH + cbase] = pk;
}

// ---------------------------------------------------------------------------
// GEMM1: 256x256 tile, BK=64, 8 waves, 8-phase pipelined schedule with
// counted vmcnt(4), K-half-split LDS regions, XOR-swizzled pair-packed layout.
// Verified R4: bank-conflict 0, steady-state ~57% of peak. Unchanged.
// ---------------------------------------------------------------------------
__global__ __launch_bounds__(512, 2)
void gemm1_8ph(const __hip_bfloat16* __restrict__ A,
               const __hip_bfloat16* __restrict__ Bt,
               const float* __restrict__ bias,
               __hip_bfloat16* __restrict__ out,
               const int* __restrict__ total_ptr) {
  constexpr int K = SIXH;     // 1536
  constexpr int NT = K / 64;  // 24 K-tiles
  constexpr int N = FOURH;    // 1024

  extern __shared__ __align__(16) char lds[];

  int total = total_ptr[0];
  int padded = (total + 255) & ~255;

  int flat = blockIdx.y * 4 + blockIdx.x;
  int xcd = flat & 7, idx = flat >> 3;
  int mt = (idx >> 2) * 8 + xcd;  // 0..199
  int nt = idx & 3;               // 0..3
  int m0 = mt * 256;
  int n0 = nt * 256;
  if (m0 >= padded) return;

  int tid = threadIdx.x;
  int lane = tid & 63;
  int w = tid >> 6;
  int wave_m = w >> 2;
  int wave_n = w & 3;

  int r15 = lane & 15, g = lane >> 4;
  int slot_r = (((r15 & 1) << 2) | g) ^ (r15 >> 1);
  int lane_off = (r15 >> 1) * 128 + slot_r * 16;

  int s0 = (tid & 7) ^ ((tid >> 3) & 7);
  int scol = (s0 & 3) * 8;
  int row0 = ((tid >> 3) << 1) + (s0 >> 2);
  int ldst0 = w * 1024;

#define REGA(d, h) (lds + (d) * 65536 + (h) * 16384)
#define REGB(d, h) (lds + (d) * 65536 + 32768 + (h) * 16384)

#define STAGE(P, t0, kt, h, rb)                                                \
  do {                                                                         \
    __builtin_amdgcn_global_load_lds(                                          \
        (gbl_void*)((P) + (size_t)((t0) + row0) * K + (kt) * 64 + (h) * 32 +   \
                    scol),                                                     \
        (lds_void*)((rb) + ldst0), 16, 0, 0);                                  \
    __builtin_amdgcn_global_load_lds(                                          \
        (gbl_void*)((P) + (size_t)((t0) + row0 + 128) * K + (kt) * 64 +        \
                    (h) * 32 + scol),                                          \
        (lds_void*)((rb) + 8192 + ldst0), 16, 0, 0);                           \
  } while (0)

  f32x4 acc[8][4] = {};

  STAGE(A, m0, 0, 0, REGA(0, 0));
  STAGE(Bt, n0, 0, 0, REGB(0, 0));
  STAGE(A, m0, 0, 1, REGA(0, 1));
  STAGE(Bt, n0, 0, 1, REGB(0, 1));
  STAGE(A, m0, 1, 0, REGA(1, 0));
  STAGE(Bt, n0, 1, 0, REGB(1, 0));
  VMCNT4();
  ASM_BAR();

  for (int kt = 0; kt < NT; ++kt) {
    int d = kt & 1;
    int kc1 = (kt + 1 < NT) ? kt + 1 : NT - 1;
    int kc2 = (kt + 2 < NT) ? kt + 2 : NT - 1;
    char* A0 = REGA(d, 0); char* A1 = REGA(d, 1);
    char* B0 = REGB(d, 0); char* B1 = REGB(d, 1);
    char* An1 = REGA(d ^ 1, 1);
    char* Bn1 = REGB(d ^ 1, 1);

    short8 a[4], b[4];

    // ---- phase 0: kh0, mi 0-3 ; stage A(kt+1, kh1)
#pragma unroll
    for (int ni = 0; ni < 4; ni++)
      b[ni] = *(const short8*)(B0 + (wave_n * 64 + ni * 16) * 64 + lane_off);
#pragma unroll
    for (int j = 0; j < 4; j++)
      a[j] = *(const short8*)(A0 + (wave_m * 128 + j * 16) * 64 + lane_off);
    STAGE(A, m0, kc1, 1, An1);
    ASM_BAR();
    __builtin_amdgcn_s_setprio(1);
#pragma unroll
    for (int j = 0; j < 4; j++)
#pragma unroll
      for (int ni = 0; ni < 4; ni++)
        acc[j][ni] =
            __builtin_amdgcn_mfma_f32_16x16x32_bf16(a[j], b[ni], acc[j][ni], 0, 0, 0);
    __builtin_amdgcn_s_setprio(0);
    ASM_BAR();

    // ---- phase 1: kh0, mi 4-7 ; stage B(kt+1, kh1)
#pragma unroll
    for (int j = 0; j < 4; j++)
      a[j] = *(const short8*)(A0 + (wave_m * 128 + (4 + j) * 16) * 64 + lane_off);
    STAGE(Bt, n0, kc1, 1, Bn1);
    ASM_BAR();
    __builtin_amdgcn_s_setprio(1);
#pragma unroll
    for (int j = 0; j < 4; j++)
#pragma unroll
      for (int ni = 0; ni < 4; ni++)
        acc[4 + j][ni] =
            __builtin_amdgcn_mfma_f32_16x16x32_bf16(a[j], b[ni], acc[4 + j][ni], 0, 0, 0);
    __builtin_amdgcn_s_setprio(0);
    ASM_BAR();

    // ---- phase 2: kh1, mi 0-3 ; stage A(kt+2, kh0) -> overwrites A0 (dead)
#pragma unroll
    for (int ni = 0; ni < 4; ni++)
      b[ni] = *(const short8*)(B1 + (wave_n * 64 + ni * 16) * 64 + lane_off);
#pragma unroll
    for (int j = 0; j < 4; j++)
      a[j] = *(const short8*)(A1 + (wave_m * 128 + j * 16) * 64 + lane_off);
    STAGE(A, m0, kc2, 0, A0);
    ASM_BAR();
    __builtin_amdgcn_s_setprio(1);
#pragma unroll
    for (int j = 0; j < 4; j++)
#pragma unroll
      for (int ni = 0; ni < 4; ni++)
        acc[j][ni] =
            __builtin_amdgcn_mfma_f32_16x16x32_bf16(a[j], b[ni], acc[j][ni], 0, 0, 0);
    __builtin_amdgcn_s_setprio(0);
    ASM_BAR();

    // ---- phase 3: kh1, mi 4-7 ; stage B(kt+2, kh0) ; counted vmcnt(4)
#pragma unroll
    for (int j = 0; j < 4; j++)
      a[j] = *(const short8*)(A1 + (wave_m * 128 + (4 + j) * 16) * 64 + lane_off);
    STAGE(Bt, n0, kc2, 0, B0);
    ASM_BAR();
    __builtin_amdgcn_s_setprio(1);
#pragma unroll
    for (int j = 0; j < 4; j++)
#pragma unroll
      for (int ni = 0; ni < 4; ni++)
        acc[4 + j][ni] =
            __builtin_amdgcn_mfma_f32_16x16x32_bf16(a[j], b[ni], acc[4 + j][ni], 0, 0, 0);
    __builtin_amdgcn_s_setprio(0);
    VMCNT4();
    ASM_BAR();
  }
  VMCNT0();

  int r0 = g * 4;
  int cc = r15;
#pragma unroll
  for (int mi = 0; mi < 8; mi++)
#pragma unroll
    for (int ni = 0; ni < 4; ni++) {
      int col = n0 + wave_n * 64 + ni * 16 + cc;
      float bv = bias[col];
#pragma unroll
      for (int r = 0; r < 4; r++) {
        int row = m0 + wave_m * 128 + mi * 16 + r0 + r;
        float v = acc[mi][ni][r] + bv;
        v = v / (1.0f + __expf(-v));  // silu
        out[(size_t)row * N + col] = __float2bfloat16(v);
      }
    }
#undef STAGE
#undef REGA
#undef REGB
}

// ---------------------------------------------------------------------------
// GEMM2 with fused scatter epilogue: C = h * w2t^T + b2, written directly
// to d_out at tpos[row] with pos_emb added. Token positions only; sep/empty
// handled by merge2. 128x128 tile, linear-LDS global_load_lds (verified).
// ---------------------------------------------------------------------------
__global__ void gemm2_scatter(const __hip_bfloat16* __restrict__ A,
                              const __hip_bfloat16* __restrict__ Bt,
                              const float* __restrict__ bias,
                              const int* __restrict__ tpos,
                              const float* __restrict__ pos_emb,
                              float* __restrict__ out,
                              const int* __restrict__ total_ptr,
                              int N, int K) {
  int m0 = blockIdx.y * 128;
  int total = total_ptr[0];
  int padded = (total + 127) & ~127;
  if (m0 >= padded) return;

  __shared__ __hip_bfloat16 As[128 * 64];
  __shared__ __hip_bfloat16 Bs[128 * 64];
  int n0 = blockIdx.x * 128;
  int tid = threadIdx.x;
  int lane = tid & 63, wid = tid >> 6;
  int wm = (wid >> 1) * 64, wn = (wid & 1) * 64;

  int srow = (lane >> 3);
  int scol = (lane & 7) * 8;

  f32x4 acc[4][4] = {};

  for (int k0 = 0; k0 < K; k0 += 64) {
#pragma unroll
    for (int i = 0; i < 4; i++) {
      int c = wid * 4 + i;
      int row = c * 8 + srow;
      __builtin_amdgcn_global_load_lds(
          (gbl_void*)&A[(size_t)(m0 + row) * K + k0 + scol],
          (lds_void*)(As + c * 512), 16, 0, 0);
      __builtin_amdgcn_global_load_lds(
          (gbl_void*)&Bt[(size_t)(n0 + row) * K + k0 + scol],
          (lds_void*)(Bs + c * 512), 16, 0, 0);
    }
    __syncthreads();
#pragma unroll
    for (int kk = 0; kk < 64; kk += 32) {
      short8 a[4], bb[4];
#pragma unroll
      for (int m = 0; m < 4; m++)
        a[m] = *(const short8*)&As[(wm + m * 16 + (lane & 15)) * 64 + kk +
                                   8 * (lane >> 4)];
#pragma unroll
      for (int n = 0; n < 4; n++)
        bb[n] = *(const short8*)&Bs[(wn + n * 16 + (lane & 15)) * 64 + kk +
                                    8 * (lane >> 4)];
#pragma unroll
      for (int m = 0; m < 4; m++)
#pragma unroll
        for (int n = 0; n < 4; n++)
          acc[m][n] = __builtin_amdgcn_mfma_f32_16x16x32_bf16(a[m], bb[n],
                                                              acc[m][n], 0, 0, 0);
    }
    __syncthreads();
  }

  int r0 = (lane >> 4) * 4;
  int cc = lane & 15;
#pragma unroll
  for (int m = 0; m < 4; m++) {
    // per-row scatter target (same for all n,cc of this row)
#pragma unroll
    for (int r = 0; r < 4; r++) {
      int row = m0 + wm + m * 16 + r0 + r;
      if (row >= total) continue;
      int pa = tpos[row];
      if (pa < 0) continue;
      int p = pa & (MAXT - 1);
#pragma unroll
      for (int n = 0; n < 4; n++) {
        int col = n0 + wn + n * 16 + cc;
        float v = acc[m][n][r] + bias[col] + pos_emb[p * H_ + col];
        out[(size_t)pa * H_ + col] = v;
      }
    }
  }
}

// ---------------------------------------------------------------------------
// merge2: sep rows (sep_token + pos_emb), zero-fill empty positions, mm.
// Token positions already written by gemm2_scatter.
// ---------------------------------------------------------------------------
__global__ void merge2_kernel(const int* __restrict__ gids,
                              const int* __restrict__ lengths,
                              const float* __restrict__ sep_token,
                              const float* __restrict__ pos_emb,
                              float* __restrict__ out) {
  int b = blockIdx.x, t = threadIdx.x;
  __shared__ signed char src[MAXT];  // 0 empty, 1 sep, 2 token
  __shared__ int g[L_];
  __shared__ int sh_total;
  int len = lengths[b];
  src[t] = 0;
  for (int l = t; l < len; l += 256) g[l] = gids[b * L_ + l];
  __syncthreads();
  if (t == 0) {
    int nsep = 0;
    for (int l = 0; l + 1 < len; l++)
      if (g[l] != g[l + 1]) nsep++;
    int total = len + nsep;
    sh_total = total;
    int off = MAXT - total;
    int sb = 0;
    for (int l = 0; l < len; l++) {
      int ti = off + l + sb;
      if (ti >= 0) src[ti] = 2;
      if (l + 1 < len && g[l] != g[l + 1]) {
        if (ti + 1 >= 0) src[ti + 1] = 1;
        sb++;
      }
    }
  }
  __syncthreads();
  int total = sh_total;
  int mlen = min(total, MAXT);

  int q = t >> 6, lane = t & 63, c4 = lane * 4;
  float4 sep4 = *(const float4*)&sep_token[c4];
  float* orow = out + (size_t)b * MAXT * H_;
  for (int p0 = 0; p0 < MAXT; p0 += 4) {
    int p = p0 + q;
    int s = src[p];
    if (s == 2) continue;  // token: written by gemm2_scatter
    float4 v;
    if (s == 1) {
      float4 pe = *(const float4*)&pos_emb[p * H_ + c4];
      v.x = sep4.x + pe.x; v.y = sep4.y + pe.y;
      v.z = sep4.z + pe.z; v.w = sep4.w + pe.w;
    } else {
      v.x = 0.f; v.y = 0.f; v.z = 0.f; v.w = 0.f;
    }
    *(float4*)&orow[(size_t)p * H_ + c4] = v;
  }
  float* mm = out + (size_t)B_ * MAXT * H_;
  mm[b * MAXT + t] = (t >= MAXT - mlen) ? 1.0f : 0.0f;
}

// ---------------------------------------------------------------------------
// launch
// ---------------------------------------------------------------------------
extern "C" void kernel_launch(void* const* d_in, const int* in_sizes, int n_in,
                              void* d_out, int out_size, void* d_ws,
                              size_t ws_size, hipStream_t stream) {
  const int* tok0 = (const int*)d_in[0];
  const int* tok1 = (const int*)d_in[1];
  const int* tok2 = (const int*)d_in[2];
  const int* tok3 = (const int*)d_in[3];
  const int* tgap = (const int*)d_in[4];
  const int* gid  = (const int*)d_in[5];
  const int* lengths = (const int*)d_in[6];
  const float* token_emb = (const float*)d_in[7];
  const float* gamma = (const float*)d_in[8];
  const float* beta  = (const float*)d_in[9];
  const float* w1 = (const float*)d_in[10];
  const float* b1 = (const float*)d_in[11];
  const float* w2 = (const float*)d_in[12];
  const float* b2 = (const float*)d_in[13];
  const float* tg_emb = (const float*)d_in[14];
  const float* g_emb  = (const float*)d_in[15];
  const float* pos_emb = (const float*)d_in[16];
  const float* sep_tok = (const float*)d_in[17];

  // workspace layout (bytes):
  //   x     bf16 [<=51200][1536] @ 0          (157,286,400)
  //   tpos  int  [<=51200]       @ 0          (aliases x; written after GEMM1)
  //   h     bf16 [<=51200][1024] @ 157286400  (104,857,600)
  //   w1t   bf16 [1024][1536]    @ 262144000  (  3,145,728)
  //   w2t   bf16 [256][1024]     @ 265289728  (    524,288)
  //   offsets int[257]           @ 265814016  (      1,028)
  const size_t NEEDED = 265815044;
  if (ws_size < NEEDED) return;

  char* ws = (char*)d_ws;
  __hip_bfloat16* x = (__hip_bfloat16*)ws;
  int* tpos = (int*)ws;  // aliases x (x dead after GEMM1)
  __hip_bfloat16* h = (__hip_bfloat16*)(ws + 157286400);
  __hip_bfloat16* w1t = (__hip_bfloat16*)(ws + 262144000);
  __hip_bfloat16* w2t = (__hip_bfloat16*)(ws + 265289728);
  int* offsets = (int*)(ws + 265814016);

  scan_offsets<<<1, 64, 0, stream>>>(lengths, offsets);
  zero_pad_x<<<256, 256, 0, stream>>>(x, offsets);

  transpose_to_bf16<<<dim3(1024 / 32, 1536 / 32), 256, 0, stream>>>(w1, w1t,
                                                                    1536, 1024);
  transpose_to_bf16<<<dim3(256 / 32, 1024 / 32), 256, 0, stream>>>(w2, w2t,
                                                                   1024, 256);

  embed_ln_kernel<<<dim3(L_, B_), 384, 0, stream>>>(
      tok0, tok1, tok2, tok3, tgap, gid, lengths, offsets, token_emb, tg_emb,
      g_emb, gamma, beta, x);

  hipFuncSetAttribute((const void*)gemm1_8ph,
                      hipFuncAttributeMaxDynamicSharedMemorySize, 131072);
  gemm1_8ph<<<dim3(4, NPOS / 256), 512, 131072, stream>>>(x, w1t, b1, h,
                                                          offsets + B_);

  // x now dead -> tpos may overwrite its region
  tpos_kernel<<<B_, 64, 0, stream>>>(gid, lengths, offsets, tpos);

  gemm2_scatter<<<dim3(H_ / 128, NPOS / 128), 256, 0, stream>>>(
      h, w2t, b2, tpos, pos_emb, (float*)d_out, offsets + B_, H_, FOURH);

  merge2_kernel<<<B_, 256, 0, stream>>>(gid, lengths, sep_tok, pos_emb,
                                        (float*)d_out);
}